// Round 12
// baseline (331.056 us; speedup 1.0000x reference)
//
#include <hip/hip_runtime.h>
#include <hip/hip_cooperative_groups.h>
#include <math.h>

namespace cg = cooperative_groups;

#define N_ANCHORS 2048
#define THRESH 0.3f
#define OVERLAP 0.5f
#define NBC 32
#define TRI(k, w) ((k) * ((k) + 1) / 2 + (w))

// ---- workspace layout ----
// head: Vs[32] | asc: masked scores, anchor order (32*2048 f32) | abox (8*2048 f2)
#define OFF_VS    0
#define OFF_ASC   128
#define OFF_ABOX  (128 + 262144)
#define HEAD      (128 + 262144 + 131072)     // 393344
// per-bc: sorted arrays + full triangular suppression matrix (528 word-units)
#define POFF_SBOX 0
#define POFF_SSC  16384
#define POFF_SID  24576
#define POFF_MAT  28672                        // u64[528*64] = 270336 B
#define PSTRIDE   299008
#define WS_NEED   (HEAD + (size_t)NBC * PSTRIDE)   // ~9.96 MB

// ==================== cooperative fused kernel: 256 blocks x 512 ====================
__global__ __launch_bounds__(512) void det_coop(
    const float* __restrict__ loc, const float* __restrict__ cls,
    const float* __restrict__ defs, float* __restrict__ out,
    unsigned char* __restrict__ ws)
{
#pragma clang fp contract(off)
    cg::grid_group grid = cg::this_grid();
    const int tid = threadIdx.x, lane = tid & 63, seg = tid >> 6;
    const int blk = blockIdx.x;                 // 0..255

    int*    Vs   = (int*)(ws + OFF_VS);
    float*  asc  = (float*)(ws + OFF_ASC);
    float2* abox = (float2*)(ws + OFF_ABOX);

    __shared__ int part[512];
    __shared__ unsigned long long s_kv[32];

    // ---------------- P0: decode + softmax (once per (b,n)), masked scores ----------------
    if (blk < 32) {
        const int idx = blk * 512 + tid;        // == b*2048 + n
        const int b = idx >> 11, n = idx & 2047;
        const float* cp = cls + (size_t)idx * 5;
        float x0 = cp[0], x1 = cp[1], x2 = cp[2], x3 = cp[3], x4 = cp[4];
        float m  = fmaxf(fmaxf(fmaxf(fmaxf(x0, x1), x2), x3), x4);
        float e0 = expf(x0 - m), e1 = expf(x1 - m), e2 = expf(x2 - m),
              e3 = expf(x3 - m), e4 = expf(x4 - m);
        float sum = e0 + e1 + e2 + e3 + e4;

        const float* lp = loc + (size_t)idx * 2;
        float l0 = lp[0], l1 = lp[1];
        float d0 = defs[n * 2 + 0], d1 = defs[n * 2 + 1];
        float cc = d0 + l0 * d1;
        float w  = d1 * expf(l1);
        abox[idx] = make_float2(cc - 0.5f * w, cc + 0.5f * w);

        float s;
        s = e1 / sum; asc[(((b << 2) + 0) << 11) + n] = (s > THRESH) ? s : -INFINITY;
        s = e2 / sum; asc[(((b << 2) + 1) << 11) + n] = (s > THRESH) ? s : -INFINITY;
        s = e3 / sum; asc[(((b << 2) + 2) << 11) + n] = (s > THRESH) ? s : -INFINITY;
        s = e4 / sum; asc[(((b << 2) + 3) << 11) + n] = (s > THRESH) ? s : -INFINITY;
    } else if (blk == 32 && tid < 32) {
        Vs[tid] = 0;
    }
    __threadfence();
    grid.sync();

    // ---------------- P1: counting rank over all 2048 masked scores ----------------
    // rank(q) = #{i: s_i > s_q or (s_i == s_q && i < q)} == stable argsort(-masked).
    // Valid items occupy ranks [0,V); invalid (-inf) land after and are not written.
#pragma unroll 1
    for (int uu = 0; uu < 4; ++uu) {
        const int u  = (blk << 2) + uu;         // 0..1023
        const int bc = u >> 5, j = u & 31;
        const int aq = (j << 6) + lane;
        const float* sc_bc = asc + (bc << 11);
        const float mq = sc_bc[aq];
        int r = 0;
        const float4* s4p = (const float4*)sc_bc;
        const int i40 = seg << 6;               // segment: 64 float4 = 256 scores
#pragma unroll 4
        for (int t4 = 0; t4 < 64; ++t4) {
            float4 s4 = s4p[i40 + t4];
            int ib = (i40 + t4) << 2;
            r += (s4.x > mq || (s4.x == mq && ib + 0 < aq)) ? 1 : 0;
            r += (s4.y > mq || (s4.y == mq && ib + 1 < aq)) ? 1 : 0;
            r += (s4.z > mq || (s4.z == mq && ib + 2 < aq)) ? 1 : 0;
            r += (s4.w > mq || (s4.w == mq && ib + 3 < aq)) ? 1 : 0;
        }
        part[tid] = r;
        __syncthreads();
        if (seg == 0) {
            int R = 0;
#pragma unroll
            for (int s = 0; s < 8; ++s) R += part[lane + (s << 6)];
            bool valid = mq > THRESH;
            unsigned long long vb = __ballot(valid);
            if (valid) {
                unsigned char* pb = ws + HEAD + (size_t)bc * PSTRIDE;
                ((float2*)(pb + POFF_SBOX))[R] = abox[((bc >> 2) << 11) + aq];
                ((float*)(pb + POFF_SSC))[R]   = mq;
                ((unsigned short*)(pb + POFF_SID))[R] = (unsigned short)aq;
            }
            if (lane == 0) atomicAdd(&Vs[bc], __popcll(vb));
        }
        __syncthreads();
    }
    __threadfence();
    grid.sync();

    // ---------------- P2: full triangular suppression matrix ----------------
#pragma unroll 1
    for (int uu = 0; uu < 4; ++uu) {
        const int u  = (blk << 2) + uu;
        const int bc = u >> 5, g = u & 31;
        const int V  = Vs[bc];
        if ((g << 6) >= V) continue;
        unsigned char* pb = ws + HEAD + (size_t)bc * PSTRIDE;
        const float2* sbox = (const float2*)(pb + POFF_SBOX);
        unsigned long long* mat = (unsigned long long*)(pb + POFF_MAT);

        const int ui = (g << 6) + lane;
        float2 ub = (ui < V) ? sbox[ui] : make_float2(1e30f, 1e30f);
        float  ul = ub.y - ub.x;
        for (int w = seg; w <= g; w += 8) {     // words round-robin over 8 waves
            const float4* sb4 = (const float4*)(sbox + (w << 6));
            unsigned long long word = 0ull;
            for (int jj = 0; jj < 32; ++jj) {
                float4 bp = sb4[jj];
                float in0 = fmaxf(fminf(ub.y, bp.y) - fmaxf(ub.x, bp.x), 0.0f);
                float un0 = (bp.y - bp.x) + ul - in0;
                float io0 = in0 / fmaxf(un0, 1e-12f);
                float in1 = fmaxf(fminf(ub.y, bp.w) - fmaxf(ub.x, bp.z), 0.0f);
                float un1 = (bp.w - bp.z) + ul - in1;
                float io1 = in1 / fmaxf(un1, 1e-12f);
                if (io0 > OVERLAP) word |= (1ull << (2 * jj));
                if (io1 > OVERLAP) word |= (1ull << (2 * jj + 1));
            }
            if (w == g) word &= (1ull << lane) - 1ull;      // diagonal: only j < u
            { int rem = V - (w << 6); if (rem < 64) word &= (1ull << rem) - 1ull; }
            if (ui >= V) word = 0ull;
            mat[((size_t)TRI(g, w) << 6) + lane] = word;
        }
    }
    __threadfence();
    grid.sync();

    // ---------------- P3: greedy fixpoint + zero + scatter (blocks 0..31) ----------------
    if (blk < 32) {
        const int bc = blk;
        const int V  = Vs[bc];
        unsigned char* pb = ws + HEAD + (size_t)bc * PSTRIDE;
        const float2*             sbox = (const float2*)(pb + POFF_SBOX);
        const float*              ssc  = (const float*)(pb + POFF_SSC);
        const unsigned short*     sid  = (const unsigned short*)(pb + POFF_SID);
        const unsigned long long* mat  = (const unsigned long long*)(pb + POFF_MAT);

        // zero this bc's output slab (out touched ONLY in P3 -> no cross-XCD WAW)
        float* outb = out + (size_t)bc * N_ANCHORS * 3;
        {
            float4 z4 = make_float4(0.f, 0.f, 0.f, 0.f);
            float4* ob4 = (float4*)outb;
            for (int i = tid; i < (N_ANCHORS * 3) / 4; i += 512) ob4[i] = z4;
        }
        if (tid < 32) s_kv[tid] = 0ull;
        __syncthreads();

        const int W = (V + 63) >> 6;
        if (seg == 0) {                          // wave 0: word-sequential fixpoint
            for (int g = 0; g < W; ++g) {
                unsigned long long dl_or = 0ull;
                for (int w = 0; w < g; ++w) {
                    unsigned long long rw = mat[((size_t)TRI(g, w) << 6) + lane];
                    dl_or |= rw & s_kv[w];
                }
                unsigned long long rself = mat[((size_t)TRI(g, g) << 6) + lane];
                int rem = V - (g << 6);
                unsigned long long valid = (rem >= 64) ? ~0ull : ((1ull << rem) - 1ull);
                unsigned long long cand = valid & ~__ballot(dl_or != 0ull);
                unsigned long long kw = 0ull;
                while (cand) {                   // in-word greedy levels
                    unsigned long long suppw = __ballot((rself & cand) != 0ull);
                    unsigned long long nk = cand & ~suppw;
                    if (!nk) nk = cand & (~cand + 1ull);     // acyclic: unreachable
                    kw |= nk;
                    unsigned long long ddw = __ballot((rself & nk) != 0ull);
                    cand &= ~(nk | ddw);
                }
                if (lane == 0) s_kv[g] = kw;
            }
        }
        __syncthreads();

        for (int r = tid; r < V; r += 512) {
            if ((s_kv[r >> 6] >> (r & 63)) & 1ull) {
                float2 bx = sbox[r];
                if (bx.x > -10.0f && bx.y < 10.0f) {
                    int n = sid[r];
                    float* o = outb + (size_t)n * 3;
                    o[0] = bx.x;
                    o[1] = bx.y;
                    o[2] = ssc[r];
                }
            }
        }
    }
}

// =============== fallback: monolithic kernel (ws too small) ===============
#define BLOCK 512
#define OFF_CSC   0
#define OFF_CBX   8208
#define OFF_CID   24592
#define OFF_SBOX  0
#define OFF_SSC   16896
#define OFF_SID   25088
#define POOL_SZ   29184

__global__ __launch_bounds__(BLOCK) void det_mono(
    const float* __restrict__ loc, const float* __restrict__ cls,
    const float* __restrict__ defs, float* __restrict__ out)
{
#pragma clang fp contract(off)
    const int tid  = threadIdx.x;
    const int lane = tid & 63;
    const int wid  = tid >> 6;
    const int bc   = blockIdx.x;
    const int b    = bc >> 2;
    const int c    = bc & 3;

    __shared__ __align__(16) unsigned char pool[POOL_SZ];
    __shared__ __align__(16) unsigned long long suprowT[8 * 512];
    __shared__ unsigned long long keptg[32];
    __shared__ unsigned long long s_deadw[8];
    __shared__ int s_wsum[8], s_woff[8], s_V;

    float*          csc  = (float*)(pool + OFF_CSC);
    float2*         cbx  = (float2*)(pool + OFF_CBX);
    unsigned short* cid  = (unsigned short*)(pool + OFF_CID);
    float2*         sbox = (float2*)(pool + OFF_SBOX);
    float*          ssc  = (float*)(pool + OFF_SSC);
    unsigned short* sid  = (unsigned short*)(pool + OFF_SID);

    float* const outb = out + (size_t)bc * N_ANCHORS * 3;
    {
        float4 z4 = make_float4(0.f, 0.f, 0.f, 0.f);
        float4* ob4 = (float4*)outb;
        for (int i = tid; i < (N_ANCHORS * 3) / 4; i += BLOCK) ob4[i] = z4;
    }
    if (tid < 32) keptg[tid] = 0ull;

    const int base = tid * 4;
    float c20[20], l8v[8], d8v[8];
    {
        const float4* cp4 = (const float4*)(cls + ((size_t)b * N_ANCHORS + base) * 5);
#pragma unroll
        for (int q = 0; q < 5; ++q) ((float4*)c20)[q] = cp4[q];
        const float4* lp4 = (const float4*)(loc + ((size_t)b * N_ANCHORS + base) * 2);
        ((float4*)l8v)[0] = lp4[0]; ((float4*)l8v)[1] = lp4[1];
        const float4* dp4 = (const float4*)(defs + (size_t)base * 2);
        ((float4*)d8v)[0] = dp4[0]; ((float4*)d8v)[1] = dp4[1];
    }
    float sc4[4], bs4[4], be4[4];
    int vmask = 0, cnt = 0;
#pragma unroll
    for (int k = 0; k < 4; ++k) {
        float x0 = c20[5*k+0], x1 = c20[5*k+1], x2 = c20[5*k+2],
              x3 = c20[5*k+3], x4 = c20[5*k+4];
        float m  = fmaxf(fmaxf(fmaxf(fmaxf(x0, x1), x2), x3), x4);
        float e0 = expf(x0 - m), e1 = expf(x1 - m), e2 = expf(x2 - m),
              e3 = expf(x3 - m), e4 = expf(x4 - m);
        float sum = e0 + e1 + e2 + e3 + e4;
        float ec  = (c == 0) ? e1 : (c == 1) ? e2 : (c == 2) ? e3 : e4;
        float score = ec / sum;
        float l0 = l8v[2*k], l1 = l8v[2*k+1];
        float d0 = d8v[2*k], d1 = d8v[2*k+1];
        float cc = d0 + l0 * d1;
        float w  = d1 * expf(l1);
        sc4[k] = score;
        bs4[k] = cc - 0.5f * w;
        be4[k] = cc + 0.5f * w;
        if (score > THRESH) { vmask |= (1 << k); cnt++; }
    }

    int inc = cnt;
    for (int d = 1; d < 64; d <<= 1) {
        int v = __shfl_up(inc, d);
        if (lane >= d) inc += v;
    }
    if (lane == 63) s_wsum[wid] = inc;
    __syncthreads();
    if (tid == 0) {
        int o = 0;
        for (int w = 0; w < 8; ++w) { s_woff[w] = o; o += s_wsum[w]; }
        s_V = o;
    }
    __syncthreads();
    {
        int off = s_woff[wid] + (inc - cnt);
#pragma unroll
        for (int k = 0; k < 4; ++k) {
            if (vmask & (1 << k)) {
                csc[off] = sc4[k];
                cbx[off] = make_float2(bs4[k], be4[k]);
                cid[off] = (unsigned short)(base + k);
                off++;
            }
        }
    }
    __syncthreads();
    const int V = s_V;
    const int SCend = ((V + 511) >> 9) << 9;
    if (tid < 4) csc[V + tid] = -INFINITY;
    __syncthreads();

#define RANKCMP(sv, ib, off2, mref, rref)                                   \
    rref += ((sv) > (mref) || ((sv) == (mref) && (ib) + (off2) < pcmp)) ? 1 : 0;
    int rr[4]; float2 rb[4]; float rs[4]; int ridv[4]; int nown = 0;
    if (V <= 512) {
        if (tid < 256) {
            int   p0 = tid, p1 = tid + 256;
            bool  a0 = p0 < V, a1 = p1 < V;
            float m0 = a0 ? csc[p0] : INFINITY;
            float m1 = a1 ? csc[p1] : INFINITY;
            int   r0 = 0, r1 = 0;
            const float4* cs4 = (const float4*)csc;
            const int n4 = (V + 3) >> 2;
            for (int i4 = 0; i4 < n4; ++i4) {
                float4 s4 = cs4[i4];
                int ib = i4 << 2;
                { int pcmp = p0;
                  RANKCMP(s4.x, ib, 0, m0, r0) RANKCMP(s4.y, ib, 1, m0, r0)
                  RANKCMP(s4.z, ib, 2, m0, r0) RANKCMP(s4.w, ib, 3, m0, r0) }
                { int pcmp = p1;
                  RANKCMP(s4.x, ib, 0, m1, r1) RANKCMP(s4.y, ib, 1, m1, r1)
                  RANKCMP(s4.z, ib, 2, m1, r1) RANKCMP(s4.w, ib, 3, m1, r1) }
            }
            if (a0) { rr[nown] = r0; rb[nown] = cbx[p0]; rs[nown] = m0; ridv[nown] = cid[p0]; nown++; }
            if (a1) { rr[nown] = r1; rb[nown] = cbx[p1]; rs[nown] = m1; ridv[nown] = cid[p1]; nown++; }
        }
    } else {
        for (int p = tid; p < V; p += BLOCK) {
            float s = csc[p];
            int r = 0;
            const float4* cs4 = (const float4*)csc;
            const int n4 = (V + 3) >> 2;
            for (int i4 = 0; i4 < n4; ++i4) {
                float4 s4 = cs4[i4];
                int ib = i4 << 2;
                int pcmp = p;
                RANKCMP(s4.x, ib, 0, s, r) RANKCMP(s4.y, ib, 1, s, r)
                RANKCMP(s4.z, ib, 2, s, r) RANKCMP(s4.w, ib, 3, s, r)
            }
            rr[nown] = r; rb[nown] = cbx[p]; rs[nown] = s; ridv[nown] = cid[p]; nown++;
        }
    }
#undef RANKCMP
    __syncthreads();
    for (int q = 0; q < nown; ++q) {
        sbox[rr[q]] = rb[q];
        ssc[rr[q]]  = rs[q];
        sid[rr[q]]  = (unsigned short)ridv[q];
    }
    for (int i = V + tid; i < SCend; i += BLOCK)
        sbox[i] = make_float2(1e30f, 1e30f);
    __syncthreads();

    for (int s0 = 0; s0 < V; s0 += 512) {
        const int scn = (V - s0 < 512) ? (V - s0) : 512;
        const int i   = tid;
        float2 my = sbox[s0 + i];
        float  ml = my.y - my.x;

        bool dead = false;
        const int ew_n = s0 >> 6;
        for (int ew = 0; ew < ew_n; ++ew) {
            unsigned long long kw = keptg[ew];
            if (kw) {
                const float4* sb4 = (const float4*)(sbox + (ew << 6));
#pragma unroll
                for (int jj = 0; jj < 32; ++jj) {
                    float4 bp = sb4[jj];
                    float in0 = fmaxf(fminf(my.y, bp.y) - fmaxf(my.x, bp.x), 0.0f);
                    float un0 = (bp.y - bp.x) + ml - in0;
                    float io0 = in0 / fmaxf(un0, 1e-12f);
                    float in1 = fmaxf(fminf(my.y, bp.w) - fmaxf(my.x, bp.z), 0.0f);
                    float un1 = (bp.w - bp.z) + ml - in1;
                    float io1 = in1 / fmaxf(un1, 1e-12f);
                    unsigned long long bits = kw >> (2 * jj);
                    dead |= (io0 > OVERLAP) && ((bits & 1ull) != 0ull);
                    dead |= (io1 > OVERLAP) && ((bits & 2ull) != 0ull);
                }
            }
        }
        {
            unsigned long long db = __ballot(dead && (i < scn));
            if (lane == 0) s_deadw[wid] = db;
        }

        {
            int t = 0;
#pragma unroll
            for (int k = 0; k < 8; ++k) {
#pragma unroll
                for (int w = 0; w <= k; ++w, ++t) {
                    if ((t & 7) == wid) {
                        const int u = (k << 6) + lane;
                        float2 ub = sbox[s0 + u];
                        float  ul = ub.y - ub.x;
                        const float4* sb4 = (const float4*)(sbox + s0 + (w << 6));
                        unsigned long long word = 0ull;
                        if (w == k) {
#pragma unroll
                            for (int jj = 0; jj < 32; ++jj) {
                                float4 bp = sb4[jj];
                                float in0 = fmaxf(fminf(ub.y, bp.y) - fmaxf(ub.x, bp.x), 0.0f);
                                float un0 = (bp.y - bp.x) + ul - in0;
                                float io0 = in0 / fmaxf(un0, 1e-12f);
                                float in1 = fmaxf(fminf(ub.y, bp.w) - fmaxf(ub.x, bp.z), 0.0f);
                                float un1 = (bp.w - bp.z) + ul - in1;
                                float io1 = in1 / fmaxf(un1, 1e-12f);
                                if (io0 > OVERLAP && 2 * jj     < lane) word |= (1ull << (2 * jj));
                                if (io1 > OVERLAP && 2 * jj + 1 < lane) word |= (1ull << (2 * jj + 1));
                            }
                        } else {
#pragma unroll
                            for (int jj = 0; jj < 32; ++jj) {
                                float4 bp = sb4[jj];
                                float in0 = fmaxf(fminf(ub.y, bp.y) - fmaxf(ub.x, bp.x), 0.0f);
                                float un0 = (bp.y - bp.x) + ul - in0;
                                float io0 = in0 / fmaxf(un0, 1e-12f);
                                float in1 = fmaxf(fminf(ub.y, bp.w) - fmaxf(ub.x, bp.z), 0.0f);
                                float un1 = (bp.w - bp.z) + ul - in1;
                                float io1 = in1 / fmaxf(un1, 1e-12f);
                                if (io0 > OVERLAP) word |= (1ull << (2 * jj));
                                if (io1 > OVERLAP) word |= (1ull << (2 * jj + 1));
                            }
                        }
                        suprowT[(w << 9) + u] = word;
                    }
                }
            }
        }
        __syncthreads();

        if (wid == 0) {
            unsigned long long row[36];
#pragma unroll
            for (int k = 0; k < 8; ++k)
#pragma unroll
                for (int w = 0; w <= k; ++w)
                    row[TRI(k, w)] = suprowT[(w << 9) + (k << 6) + lane];
            unsigned long long sdead[8];
#pragma unroll
            for (int w = 0; w < 8; ++w) sdead[w] = s_deadw[w];

            unsigned long long kv[8];
#pragma unroll
            for (int w = 0; w < 8; ++w) {
                kv[w] = 0ull;
                if ((w << 6) < scn) {
                    bool dl = ((sdead[w] >> lane) & 1ull) != 0ull;
#pragma unroll
                    for (int w2 = 0; w2 < w; ++w2)
                        dl |= (row[TRI(w, w2)] & kv[w2]) != 0ull;
                    const unsigned long long rself = row[TRI(w, w)];
                    int rem = scn - (w << 6);
                    unsigned long long valid = (rem >= 64) ? ~0ull : ((1ull << rem) - 1ull);
                    unsigned long long cand = valid & ~__ballot(dl);
                    unsigned long long kw = 0ull;
                    while (cand) {
                        unsigned long long suppw = __ballot((rself & cand) != 0ull);
                        unsigned long long nk = cand & ~suppw;
                        if (!nk) nk = cand & (~cand + 1ull);
                        kw |= nk;
                        unsigned long long ddw = __ballot((rself & nk) != 0ull);
                        cand &= ~(nk | ddw);
                    }
                    kv[w] = kw;
                }
            }
            if (lane == 0) {
#pragma unroll
                for (int w = 0; w < 8; ++w) keptg[(s0 >> 6) + w] |= kv[w];
            }
        }
        __syncthreads();
    }

    for (int r = tid; r < V; r += BLOCK) {
        if ((keptg[r >> 6] >> (r & 63)) & 1ull) {
            float2 bx = sbox[r];
            if (bx.x > -10.0f && bx.y < 10.0f) {
                int n = sid[r];
                float* o = outb + (size_t)n * 3;
                o[0] = bx.x;
                o[1] = bx.y;
                o[2] = ssc[r];
            }
        }
    }
}

extern "C" void kernel_launch(void* const* d_in, const int* in_sizes, int n_in,
                              void* d_out, int out_size, void* d_ws, size_t ws_size,
                              hipStream_t stream) {
    const float* loc  = (const float*)d_in[0];  // localizations (8,2048,2)
    const float* cls  = (const float*)d_in[1];  // classifications (8,2048,5)
    const float* defs = (const float*)d_in[2];  // localizations_default (2048,2)
    float* out = (float*)d_out;                 // (8,4,2048,3) fp32
    if (ws_size >= WS_NEED) {
        unsigned char* ws = (unsigned char*)d_ws;
        void* args[] = { (void*)&loc, (void*)&cls, (void*)&defs, (void*)&out, (void*)&ws };
        hipLaunchCooperativeKernel((const void*)det_coop, dim3(256), dim3(512),
                                   args, 0, stream);
    } else {
        det_mono<<<NBC, BLOCK, 0, stream>>>(loc, cls, defs, out);
    }
}

// Round 13
// 120.205 us; speedup vs baseline: 2.7541x; 2.7541x over previous
//
#include <hip/hip_runtime.h>
#include <math.h>

#define N_ANCHORS 2048
#define THRESH 0.3f
#define OVERLAP 0.5f
#define NBC 32
#define TRI(k, w) ((k) * ((k) + 1) / 2 + (w))

// ---- workspace layout ----
// head: Vs[32] | asc: masked scores, (b,c) x anchor order (32*2048 f32) | abox (8*2048 f2)
#define OFF_VS    0
#define OFF_ASC   128
#define OFF_ABOX  (128 + 262144)
#define HEAD      (128 + 262144 + 131072)     // 393344
// per-bc: sorted arrays + full triangular suppression matrix (528 word-units)
#define POFF_SBOX 0
#define POFF_SSC  16384
#define POFF_SID  24576
#define POFF_MAT  28672                        // u64[528*64] = 270336 B
#define PSTRIDE   299008
#define WS_NEED   (HEAD + (size_t)NBC * PSTRIDE)   // ~9.96 MB

// ========== K1: decode + softmax ONCE per (b,n); masked scores; zero out ==========
__global__ __launch_bounds__(512) void k1_decode(
    const float* __restrict__ loc, const float* __restrict__ cls,
    const float* __restrict__ defs, float* __restrict__ out,
    unsigned char* __restrict__ ws)
{
#pragma clang fp contract(off)
    const int tid = threadIdx.x, blk = blockIdx.x;     // 32 blocks
    int*    Vs   = (int*)(ws + OFF_VS);
    float*  asc  = (float*)(ws + OFF_ASC);
    float2* abox = (float2*)(ws + OFF_ABOX);

    // zero output (each thread 3 float4s)
    {
        float4 z4 = make_float4(0.f, 0.f, 0.f, 0.f);
        float4* ob4 = (float4*)out;
        for (int i = blk * 512 + tid; i < (NBC * N_ANCHORS * 3) / 4; i += 32 * 512)
            ob4[i] = z4;
    }
    if (blk == 0 && tid < 32) Vs[tid] = 0;

    const int idx = blk * 512 + tid;                   // == b*2048 + n
    const int b = idx >> 11, n = idx & 2047;
    const float* cp = cls + (size_t)idx * 5;
    float x0 = cp[0], x1 = cp[1], x2 = cp[2], x3 = cp[3], x4 = cp[4];
    float m  = fmaxf(fmaxf(fmaxf(fmaxf(x0, x1), x2), x3), x4);
    float e0 = expf(x0 - m), e1 = expf(x1 - m), e2 = expf(x2 - m),
          e3 = expf(x3 - m), e4 = expf(x4 - m);
    float sum = e0 + e1 + e2 + e3 + e4;

    const float* lp = loc + (size_t)idx * 2;
    float l0 = lp[0], l1 = lp[1];
    float d0 = defs[n * 2 + 0], d1 = defs[n * 2 + 1];
    float cc = d0 + l0 * d1;
    float w  = d1 * expf(l1);
    abox[idx] = make_float2(cc - 0.5f * w, cc + 0.5f * w);

    float s;
    s = e1 / sum; asc[(((b << 2) + 0) << 11) + n] = (s > THRESH) ? s : -INFINITY;
    s = e2 / sum; asc[(((b << 2) + 1) << 11) + n] = (s > THRESH) ? s : -INFINITY;
    s = e3 / sum; asc[(((b << 2) + 2) << 11) + n] = (s > THRESH) ? s : -INFINITY;
    s = e4 / sum; asc[(((b << 2) + 3) << 11) + n] = (s > THRESH) ? s : -INFINITY;
}

// ========== K2: counting rank over all 2048 masked scores (1024 blocks) ==========
// rank(q) = #{i: s_i > s_q or (s_i == s_q && i < q)} == stable argsort(-masked).
// Valid items occupy ranks [0,V); invalid (-inf) rank after and are not written.
// Ranks are a permutation -> scatter writes race-free across blocks.
__global__ __launch_bounds__(512) void k2_rank(unsigned char* __restrict__ ws)
{
    const int u  = blockIdx.x;                  // 0..1023
    const int bc = u >> 5, j = u & 31;
    const int tid = threadIdx.x, lane = tid & 63, seg = tid >> 6;
    int*          Vs   = (int*)(ws + OFF_VS);
    const float*  asc  = (const float*)(ws + OFF_ASC);
    const float2* abox = (const float2*)(ws + OFF_ABOX);

    __shared__ int part[512];

    const int aq = (j << 6) + lane;
    const float* sc_bc = asc + (bc << 11);
    const float mq = sc_bc[aq];
    int r = 0;
    const float4* s4p = (const float4*)sc_bc;
    const int i40 = seg << 6;                   // each seg: 64 float4 = 256 scores
#pragma unroll 4
    for (int t4 = 0; t4 < 64; ++t4) {
        float4 s4 = s4p[i40 + t4];              // wave-uniform stream (scalar loads)
        int ib = (i40 + t4) << 2;
        r += (s4.x > mq || (s4.x == mq && ib + 0 < aq)) ? 1 : 0;
        r += (s4.y > mq || (s4.y == mq && ib + 1 < aq)) ? 1 : 0;
        r += (s4.z > mq || (s4.z == mq && ib + 2 < aq)) ? 1 : 0;
        r += (s4.w > mq || (s4.w == mq && ib + 3 < aq)) ? 1 : 0;
    }
    part[tid] = r;
    __syncthreads();
    if (seg == 0) {
        int R = 0;
#pragma unroll
        for (int s = 0; s < 8; ++s) R += part[lane + (s << 6)];
        bool valid = mq > THRESH;               // -inf fails -> only valid written
        unsigned long long vb = __ballot(valid);
        if (valid) {
            unsigned char* pb = ws + HEAD + (size_t)bc * PSTRIDE;
            ((float2*)(pb + POFF_SBOX))[R] = abox[((bc >> 2) << 11) + aq];
            ((float*)(pb + POFF_SSC))[R]   = mq;
            ((unsigned short*)(pb + POFF_SID))[R] = (unsigned short)aq;
        }
        if (lane == 0) atomicAdd(&Vs[bc], __popcll(vb));
    }
}

// ========== K3: full triangular suppression matrix (stripe g per block) ==========
__global__ __launch_bounds__(512) void k3_full(unsigned char* __restrict__ ws)
{
#pragma clang fp contract(off)
    const int u  = blockIdx.x;                  // 0..1023
    const int bc = u >> 5, g = u & 31;
    const int V = ((const int*)(ws + OFF_VS))[bc];
    if ((g << 6) >= V) return;
    const int tid = threadIdx.x, lane = tid & 63, seg = tid >> 6;
    unsigned char* pb = ws + HEAD + (size_t)bc * PSTRIDE;
    const float2* sbox = (const float2*)(pb + POFF_SBOX);
    unsigned long long* mat = (unsigned long long*)(pb + POFF_MAT);

    const int ui = (g << 6) + lane;
    float2 ub = (ui < V) ? sbox[ui] : make_float2(1e30f, 1e30f);
    float  ul = ub.y - ub.x;
    for (int w = seg; w <= g; w += 8) {         // words round-robin over 8 waves
        const float4* sb4 = (const float4*)(sbox + (w << 6));
        unsigned long long word = 0ull;
        for (int jj = 0; jj < 32; ++jj) {
            float4 bp = sb4[jj];
            float in0 = fmaxf(fminf(ub.y, bp.y) - fmaxf(ub.x, bp.x), 0.0f);
            float un0 = (bp.y - bp.x) + ul - in0;
            float io0 = in0 / fmaxf(un0, 1e-12f);
            float in1 = fmaxf(fminf(ub.y, bp.w) - fmaxf(ub.x, bp.z), 0.0f);
            float un1 = (bp.w - bp.z) + ul - in1;
            float io1 = in1 / fmaxf(un1, 1e-12f);
            if (io0 > OVERLAP) word |= (1ull << (2 * jj));
            if (io1 > OVERLAP) word |= (1ull << (2 * jj + 1));
        }
        if (w == g) word &= (1ull << lane) - 1ull;          // diagonal: only j < u
        { int rem = V - (w << 6); if (rem < 64) word &= (1ull << rem) - 1ull; }
        if (ui >= V) word = 0ull;
        mat[((size_t)TRI(g, w) << 6) + lane] = word;
    }
}

// ========== K4: word-sequential greedy fixpoint (wave 0) + scatter ==========
__global__ __launch_bounds__(512) void k4_fix(
    float* __restrict__ out, unsigned char* __restrict__ ws)
{
    const int tid = threadIdx.x, lane = tid & 63, seg = tid >> 6;
    const int bc = blockIdx.x;
    const int V = ((const int*)(ws + OFF_VS))[bc];
    const unsigned char* pb = ws + HEAD + (size_t)bc * PSTRIDE;
    const float2*             sbox = (const float2*)(pb + POFF_SBOX);
    const float*              ssc  = (const float*)(pb + POFF_SSC);
    const unsigned short*     sid  = (const unsigned short*)(pb + POFF_SID);
    const unsigned long long* mat  = (const unsigned long long*)(pb + POFF_MAT);
    __shared__ unsigned long long s_kv[32];

    if (tid < 32) s_kv[tid] = 0ull;
    __syncthreads();

    const int W = (V + 63) >> 6;
    if (seg == 0) {
        for (int g = 0; g < W; ++g) {
            unsigned long long dl_or = 0ull;
            for (int w = 0; w < g; ++w) {
                unsigned long long rw = mat[((size_t)TRI(g, w) << 6) + lane];
                dl_or |= rw & s_kv[w];
            }
            unsigned long long rself = mat[((size_t)TRI(g, g) << 6) + lane];
            int rem = V - (g << 6);
            unsigned long long valid = (rem >= 64) ? ~0ull : ((1ull << rem) - 1ull);
            unsigned long long cand = valid & ~__ballot(dl_or != 0ull);
            unsigned long long kw = 0ull;
            while (cand) {                      // in-word greedy levels
                unsigned long long suppw = __ballot((rself & cand) != 0ull);
                unsigned long long nk = cand & ~suppw;
                if (!nk) nk = cand & (~cand + 1ull);    // acyclic: unreachable
                kw |= nk;
                unsigned long long ddw = __ballot((rself & nk) != 0ull);
                cand &= ~(nk | ddw);
            }
            if (lane == 0) s_kv[g] = kw;
        }
    }
    __syncthreads();

    float* outb = out + (size_t)bc * N_ANCHORS * 3;
    for (int r = tid; r < V; r += 512) {
        if ((s_kv[r >> 6] >> (r & 63)) & 1ull) {
            float2 bx = sbox[r];
            if (bx.x > -10.0f && bx.y < 10.0f) {
                int n = sid[r];
                float* o = outb + (size_t)n * 3;
                o[0] = bx.x;
                o[1] = bx.y;
                o[2] = ssc[r];
            }
        }
    }
}

// =============== fallback: monolithic kernel (ws too small) ===============
#define BLOCK 512
#define OFF_CSC   0
#define OFF_CBX   8208
#define OFF_CID   24592
#define OFF_SBOX  0
#define OFF_SSC   16896
#define OFF_SID   25088
#define POOL_SZ   29184

__global__ __launch_bounds__(BLOCK) void det_mono(
    const float* __restrict__ loc, const float* __restrict__ cls,
    const float* __restrict__ defs, float* __restrict__ out)
{
#pragma clang fp contract(off)
    const int tid  = threadIdx.x;
    const int lane = tid & 63;
    const int wid  = tid >> 6;
    const int bc   = blockIdx.x;
    const int b    = bc >> 2;
    const int c    = bc & 3;

    __shared__ __align__(16) unsigned char pool[POOL_SZ];
    __shared__ __align__(16) unsigned long long suprowT[8 * 512];
    __shared__ unsigned long long keptg[32];
    __shared__ unsigned long long s_deadw[8];
    __shared__ int s_wsum[8], s_woff[8], s_V;

    float*          csc  = (float*)(pool + OFF_CSC);
    float2*         cbx  = (float2*)(pool + OFF_CBX);
    unsigned short* cid  = (unsigned short*)(pool + OFF_CID);
    float2*         sbox = (float2*)(pool + OFF_SBOX);
    float*          ssc  = (float*)(pool + OFF_SSC);
    unsigned short* sid  = (unsigned short*)(pool + OFF_SID);

    float* const outb = out + (size_t)bc * N_ANCHORS * 3;
    {
        float4 z4 = make_float4(0.f, 0.f, 0.f, 0.f);
        float4* ob4 = (float4*)outb;
        for (int i = tid; i < (N_ANCHORS * 3) / 4; i += BLOCK) ob4[i] = z4;
    }
    if (tid < 32) keptg[tid] = 0ull;

    const int base = tid * 4;
    float c20[20], l8v[8], d8v[8];
    {
        const float4* cp4 = (const float4*)(cls + ((size_t)b * N_ANCHORS + base) * 5);
#pragma unroll
        for (int q = 0; q < 5; ++q) ((float4*)c20)[q] = cp4[q];
        const float4* lp4 = (const float4*)(loc + ((size_t)b * N_ANCHORS + base) * 2);
        ((float4*)l8v)[0] = lp4[0]; ((float4*)l8v)[1] = lp4[1];
        const float4* dp4 = (const float4*)(defs + (size_t)base * 2);
        ((float4*)d8v)[0] = dp4[0]; ((float4*)d8v)[1] = dp4[1];
    }
    float sc4[4], bs4[4], be4[4];
    int vmask = 0, cnt = 0;
#pragma unroll
    for (int k = 0; k < 4; ++k) {
        float x0 = c20[5*k+0], x1 = c20[5*k+1], x2 = c20[5*k+2],
              x3 = c20[5*k+3], x4 = c20[5*k+4];
        float m  = fmaxf(fmaxf(fmaxf(fmaxf(x0, x1), x2), x3), x4);
        float e0 = expf(x0 - m), e1 = expf(x1 - m), e2 = expf(x2 - m),
              e3 = expf(x3 - m), e4 = expf(x4 - m);
        float sum = e0 + e1 + e2 + e3 + e4;
        float ec  = (c == 0) ? e1 : (c == 1) ? e2 : (c == 2) ? e3 : e4;
        float score = ec / sum;
        float l0 = l8v[2*k], l1 = l8v[2*k+1];
        float d0 = d8v[2*k], d1 = d8v[2*k+1];
        float cc = d0 + l0 * d1;
        float w  = d1 * expf(l1);
        sc4[k] = score;
        bs4[k] = cc - 0.5f * w;
        be4[k] = cc + 0.5f * w;
        if (score > THRESH) { vmask |= (1 << k); cnt++; }
    }

    int inc = cnt;
    for (int d = 1; d < 64; d <<= 1) {
        int v = __shfl_up(inc, d);
        if (lane >= d) inc += v;
    }
    if (lane == 63) s_wsum[wid] = inc;
    __syncthreads();
    if (tid == 0) {
        int o = 0;
        for (int w = 0; w < 8; ++w) { s_woff[w] = o; o += s_wsum[w]; }
        s_V = o;
    }
    __syncthreads();
    {
        int off = s_woff[wid] + (inc - cnt);
#pragma unroll
        for (int k = 0; k < 4; ++k) {
            if (vmask & (1 << k)) {
                csc[off] = sc4[k];
                cbx[off] = make_float2(bs4[k], be4[k]);
                cid[off] = (unsigned short)(base + k);
                off++;
            }
        }
    }
    __syncthreads();
    const int V = s_V;
    const int SCend = ((V + 511) >> 9) << 9;
    if (tid < 4) csc[V + tid] = -INFINITY;
    __syncthreads();

#define RANKCMP(sv, ib, off2, mref, rref)                                   \
    rref += ((sv) > (mref) || ((sv) == (mref) && (ib) + (off2) < pcmp)) ? 1 : 0;
    int rr[4]; float2 rb[4]; float rs[4]; int ridv[4]; int nown = 0;
    if (V <= 512) {
        if (tid < 256) {
            int   p0 = tid, p1 = tid + 256;
            bool  a0 = p0 < V, a1 = p1 < V;
            float m0 = a0 ? csc[p0] : INFINITY;
            float m1 = a1 ? csc[p1] : INFINITY;
            int   r0 = 0, r1 = 0;
            const float4* cs4 = (const float4*)csc;
            const int n4 = (V + 3) >> 2;
            for (int i4 = 0; i4 < n4; ++i4) {
                float4 s4 = cs4[i4];
                int ib = i4 << 2;
                { int pcmp = p0;
                  RANKCMP(s4.x, ib, 0, m0, r0) RANKCMP(s4.y, ib, 1, m0, r0)
                  RANKCMP(s4.z, ib, 2, m0, r0) RANKCMP(s4.w, ib, 3, m0, r0) }
                { int pcmp = p1;
                  RANKCMP(s4.x, ib, 0, m1, r1) RANKCMP(s4.y, ib, 1, m1, r1)
                  RANKCMP(s4.z, ib, 2, m1, r1) RANKCMP(s4.w, ib, 3, m1, r1) }
            }
            if (a0) { rr[nown] = r0; rb[nown] = cbx[p0]; rs[nown] = m0; ridv[nown] = cid[p0]; nown++; }
            if (a1) { rr[nown] = r1; rb[nown] = cbx[p1]; rs[nown] = m1; ridv[nown] = cid[p1]; nown++; }
        }
    } else {
        for (int p = tid; p < V; p += BLOCK) {
            float s = csc[p];
            int r = 0;
            const float4* cs4 = (const float4*)csc;
            const int n4 = (V + 3) >> 2;
            for (int i4 = 0; i4 < n4; ++i4) {
                float4 s4 = cs4[i4];
                int ib = i4 << 2;
                int pcmp = p;
                RANKCMP(s4.x, ib, 0, s, r) RANKCMP(s4.y, ib, 1, s, r)
                RANKCMP(s4.z, ib, 2, s, r) RANKCMP(s4.w, ib, 3, s, r)
            }
            rr[nown] = r; rb[nown] = cbx[p]; rs[nown] = s; ridv[nown] = cid[p]; nown++;
        }
    }
#undef RANKCMP
    __syncthreads();
    for (int q = 0; q < nown; ++q) {
        sbox[rr[q]] = rb[q];
        ssc[rr[q]]  = rs[q];
        sid[rr[q]]  = (unsigned short)ridv[q];
    }
    for (int i = V + tid; i < SCend; i += BLOCK)
        sbox[i] = make_float2(1e30f, 1e30f);
    __syncthreads();

    for (int s0 = 0; s0 < V; s0 += 512) {
        const int scn = (V - s0 < 512) ? (V - s0) : 512;
        const int i   = tid;
        float2 my = sbox[s0 + i];
        float  ml = my.y - my.x;

        bool dead = false;
        const int ew_n = s0 >> 6;
        for (int ew = 0; ew < ew_n; ++ew) {
            unsigned long long kw = keptg[ew];
            if (kw) {
                const float4* sb4 = (const float4*)(sbox + (ew << 6));
#pragma unroll
                for (int jj = 0; jj < 32; ++jj) {
                    float4 bp = sb4[jj];
                    float in0 = fmaxf(fminf(my.y, bp.y) - fmaxf(my.x, bp.x), 0.0f);
                    float un0 = (bp.y - bp.x) + ml - in0;
                    float io0 = in0 / fmaxf(un0, 1e-12f);
                    float in1 = fmaxf(fminf(my.y, bp.w) - fmaxf(my.x, bp.z), 0.0f);
                    float un1 = (bp.w - bp.z) + ml - in1;
                    float io1 = in1 / fmaxf(un1, 1e-12f);
                    unsigned long long bits = kw >> (2 * jj);
                    dead |= (io0 > OVERLAP) && ((bits & 1ull) != 0ull);
                    dead |= (io1 > OVERLAP) && ((bits & 2ull) != 0ull);
                }
            }
        }
        {
            unsigned long long db = __ballot(dead && (i < scn));
            if (lane == 0) s_deadw[wid] = db;
        }

        {
            int t = 0;
#pragma unroll
            for (int k = 0; k < 8; ++k) {
#pragma unroll
                for (int w = 0; w <= k; ++w, ++t) {
                    if ((t & 7) == wid) {
                        const int u = (k << 6) + lane;
                        float2 ub = sbox[s0 + u];
                        float  ul = ub.y - ub.x;
                        const float4* sb4 = (const float4*)(sbox + s0 + (w << 6));
                        unsigned long long word = 0ull;
                        if (w == k) {
#pragma unroll
                            for (int jj = 0; jj < 32; ++jj) {
                                float4 bp = sb4[jj];
                                float in0 = fmaxf(fminf(ub.y, bp.y) - fmaxf(ub.x, bp.x), 0.0f);
                                float un0 = (bp.y - bp.x) + ul - in0;
                                float io0 = in0 / fmaxf(un0, 1e-12f);
                                float in1 = fmaxf(fminf(ub.y, bp.w) - fmaxf(ub.x, bp.z), 0.0f);
                                float un1 = (bp.w - bp.z) + ul - in1;
                                float io1 = in1 / fmaxf(un1, 1e-12f);
                                if (io0 > OVERLAP && 2 * jj     < lane) word |= (1ull << (2 * jj));
                                if (io1 > OVERLAP && 2 * jj + 1 < lane) word |= (1ull << (2 * jj + 1));
                            }
                        } else {
#pragma unroll
                            for (int jj = 0; jj < 32; ++jj) {
                                float4 bp = sb4[jj];
                                float in0 = fmaxf(fminf(ub.y, bp.y) - fmaxf(ub.x, bp.x), 0.0f);
                                float un0 = (bp.y - bp.x) + ul - in0;
                                float io0 = in0 / fmaxf(un0, 1e-12f);
                                float in1 = fmaxf(fminf(ub.y, bp.w) - fmaxf(ub.x, bp.z), 0.0f);
                                float un1 = (bp.w - bp.z) + ul - in1;
                                float io1 = in1 / fmaxf(un1, 1e-12f);
                                if (io0 > OVERLAP) word |= (1ull << (2 * jj));
                                if (io1 > OVERLAP) word |= (1ull << (2 * jj + 1));
                            }
                        }
                        suprowT[(w << 9) + u] = word;
                    }
                }
            }
        }
        __syncthreads();

        if (wid == 0) {
            unsigned long long row[36];
#pragma unroll
            for (int k = 0; k < 8; ++k)
#pragma unroll
                for (int w = 0; w <= k; ++w)
                    row[TRI(k, w)] = suprowT[(w << 9) + (k << 6) + lane];
            unsigned long long sdead[8];
#pragma unroll
            for (int w = 0; w < 8; ++w) sdead[w] = s_deadw[w];

            unsigned long long kv[8];
#pragma unroll
            for (int w = 0; w < 8; ++w) {
                kv[w] = 0ull;
                if ((w << 6) < scn) {
                    bool dl = ((sdead[w] >> lane) & 1ull) != 0ull;
#pragma unroll
                    for (int w2 = 0; w2 < w; ++w2)
                        dl |= (row[TRI(w, w2)] & kv[w2]) != 0ull;
                    const unsigned long long rself = row[TRI(w, w)];
                    int rem = scn - (w << 6);
                    unsigned long long valid = (rem >= 64) ? ~0ull : ((1ull << rem) - 1ull);
                    unsigned long long cand = valid & ~__ballot(dl);
                    unsigned long long kw = 0ull;
                    while (cand) {
                        unsigned long long suppw = __ballot((rself & cand) != 0ull);
                        unsigned long long nk = cand & ~suppw;
                        if (!nk) nk = cand & (~cand + 1ull);
                        kw |= nk;
                        unsigned long long ddw = __ballot((rself & nk) != 0ull);
                        cand &= ~(nk | ddw);
                    }
                    kv[w] = kw;
                }
            }
            if (lane == 0) {
#pragma unroll
                for (int w = 0; w < 8; ++w) keptg[(s0 >> 6) + w] |= kv[w];
            }
        }
        __syncthreads();
    }

    for (int r = tid; r < V; r += BLOCK) {
        if ((keptg[r >> 6] >> (r & 63)) & 1ull) {
            float2 bx = sbox[r];
            if (bx.x > -10.0f && bx.y < 10.0f) {
                int n = sid[r];
                float* o = outb + (size_t)n * 3;
                o[0] = bx.x;
                o[1] = bx.y;
                o[2] = ssc[r];
            }
        }
    }
}

extern "C" void kernel_launch(void* const* d_in, const int* in_sizes, int n_in,
                              void* d_out, int out_size, void* d_ws, size_t ws_size,
                              hipStream_t stream) {
    const float* loc  = (const float*)d_in[0];  // localizations (8,2048,2)
    const float* cls  = (const float*)d_in[1];  // classifications (8,2048,5)
    const float* defs = (const float*)d_in[2];  // localizations_default (2048,2)
    float* out = (float*)d_out;                 // (8,4,2048,3) fp32
    if (ws_size >= WS_NEED) {
        unsigned char* ws = (unsigned char*)d_ws;
        k1_decode<<<32, 512, 0, stream>>>(loc, cls, defs, out, ws);
        k2_rank  <<<1024, 512, 0, stream>>>(ws);
        k3_full  <<<1024, 512, 0, stream>>>(ws);
        k4_fix   <<<32, 512, 0, stream>>>(out, ws);
    } else {
        det_mono<<<NBC, BLOCK, 0, stream>>>(loc, cls, defs, out);
    }
}

// Round 14
// 119.200 us; speedup vs baseline: 2.7773x; 1.0084x over previous
//
#include <hip/hip_runtime.h>
#include <math.h>

#define N_ANCHORS 2048
#define THRESH 0.3f
#define OVERLAP 0.5f
#define NBC 32
#define TRI(k, w) ((k) * ((k) + 1) / 2 + (w))

// ---- workspace layout ----
#define OFF_VCNT  0                            // int[32*32]: per-(bc,j) valid counts
#define HEAD      4096
#define POFF_SBOX 0                            // float2[2048] box, sorted order
#define POFF_SSC  16384                        // float[2048]  score, sorted order
#define POFF_SID  24576                        // ushort[2048] anchor id, sorted order
#define POFF_MAT  28672                        // u64[528*64] triangular matrix
#define PSTRIDE   299008
#define WS_NEED   (HEAD + (size_t)NBC * PSTRIDE)   // ~9.57 MB

// ===== K2': decode+softmax (LDS) + counting rank + scatter (1024 blocks) =====
// rank(q) = #{i: s_i > s_q or (s_i == s_q && i < q)} == stable argsort(-masked).
// Valid items land in ranks [0,V); ranks are a permutation -> race-free scatter.
__global__ __launch_bounds__(512) void k2_rankdec(
    const float* __restrict__ loc, const float* __restrict__ cls,
    const float* __restrict__ defs, unsigned char* __restrict__ ws)
{
#pragma clang fp contract(off)
    const int u  = blockIdx.x;                  // 0..1023
    const int bc = u >> 5, j = u & 31;
    const int b  = bc >> 2, c = bc & 3;
    const int tid = threadIdx.x, lane = tid & 63, seg = tid >> 6;

    __shared__ __align__(16) float smask[2048]; // masked scores, anchor order
    __shared__ int part[512];

    // ---- phase A: softmax once per anchor (4 consecutive anchors/thread) ----
    {
        const int n0 = tid * 4;
        const float4* cp4 = (const float4*)(cls + ((size_t)(b << 11) + n0) * 5);
        float c20[20];
#pragma unroll
        for (int q = 0; q < 5; ++q) ((float4*)c20)[q] = cp4[q];
#pragma unroll
        for (int k = 0; k < 4; ++k) {
            float x0 = c20[5*k+0], x1 = c20[5*k+1], x2 = c20[5*k+2],
                  x3 = c20[5*k+3], x4 = c20[5*k+4];
            float m  = fmaxf(fmaxf(fmaxf(fmaxf(x0, x1), x2), x3), x4);
            float e0 = expf(x0 - m), e1 = expf(x1 - m), e2 = expf(x2 - m),
                  e3 = expf(x3 - m), e4 = expf(x4 - m);
            float sum = e0 + e1 + e2 + e3 + e4;
            float ec  = (c == 0) ? e1 : (c == 1) ? e2 : (c == 2) ? e3 : e4;
            float s   = ec / sum;
            smask[n0 + k] = (s > THRESH) ? s : -INFINITY;
        }
    }
    __syncthreads();

    // ---- phase B: counting rank from LDS (broadcast b128 reads) ----
    const int aq = (j << 6) + lane;
    const float mq = smask[aq];
    int r = 0;
    {
        const float4* s4p = (const float4*)smask;
        const int i40 = seg << 6;               // each seg scans 256 scores
#pragma unroll 4
        for (int t4 = 0; t4 < 64; ++t4) {
            float4 s4 = s4p[i40 + t4];          // same addr across lanes: broadcast
            int ib = (i40 + t4) << 2;
            r += (s4.x > mq || (s4.x == mq && ib + 0 < aq)) ? 1 : 0;
            r += (s4.y > mq || (s4.y == mq && ib + 1 < aq)) ? 1 : 0;
            r += (s4.z > mq || (s4.z == mq && ib + 2 < aq)) ? 1 : 0;
            r += (s4.w > mq || (s4.w == mq && ib + 3 < aq)) ? 1 : 0;
        }
    }
    part[tid] = r;
    __syncthreads();
    if (seg == 0) {
        int R = 0;
#pragma unroll
        for (int s = 0; s < 8; ++s) R += part[lane + (s << 6)];
        bool valid = mq > THRESH;               // -inf fails
        unsigned long long vb = __ballot(valid);
        if (valid) {
            // decode box only for winners (bit-identical expressions)
            const float* lp = loc + ((size_t)(b << 11) + aq) * 2;
            float l0 = lp[0], l1 = lp[1];
            float d0 = defs[aq * 2 + 0], d1 = defs[aq * 2 + 1];
            float cc = d0 + l0 * d1;
            float w  = d1 * expf(l1);
            unsigned char* pb = ws + HEAD + (size_t)bc * PSTRIDE;
            ((float2*)(pb + POFF_SBOX))[R] = make_float2(cc - 0.5f * w, cc + 0.5f * w);
            ((float*)(pb + POFF_SSC))[R]   = mq;
            ((unsigned short*)(pb + POFF_SID))[R] = (unsigned short)aq;
        }
        if (lane == 0)
            ((int*)(ws + OFF_VCNT))[(bc << 5) + j] = __popcll(vb);   // single writer
    }
}

// ========== K3: full triangular suppression matrix (stripe g per block) ==========
__global__ __launch_bounds__(512) void k3_full(unsigned char* __restrict__ ws)
{
#pragma clang fp contract(off)
    const int u  = blockIdx.x;                  // 0..1023
    const int bc = u >> 5, g = u & 31;
    const int* vc = (const int*)(ws + OFF_VCNT) + (bc << 5);
    int V = 0;
#pragma unroll
    for (int t = 0; t < 32; ++t) V += vc[t];    // wave-uniform scalar loads
    if ((g << 6) >= V) return;
    const int tid = threadIdx.x, lane = tid & 63, seg = tid >> 6;
    unsigned char* pb = ws + HEAD + (size_t)bc * PSTRIDE;
    const float2* sbox = (const float2*)(pb + POFF_SBOX);
    unsigned long long* mat = (unsigned long long*)(pb + POFF_MAT);

    const int ui = (g << 6) + lane;
    float2 ub = (ui < V) ? sbox[ui] : make_float2(1e30f, 1e30f);
    float  ul = ub.y - ub.x;
    for (int w = seg; w <= g; w += 8) {         // words round-robin over 8 waves
        const float4* sb4 = (const float4*)(sbox + (w << 6));
        unsigned long long word = 0ull;
        for (int jj = 0; jj < 32; ++jj) {
            float4 bp = sb4[jj];
            float in0 = fmaxf(fminf(ub.y, bp.y) - fmaxf(ub.x, bp.x), 0.0f);
            float un0 = (bp.y - bp.x) + ul - in0;
            float io0 = in0 / fmaxf(un0, 1e-12f);
            float in1 = fmaxf(fminf(ub.y, bp.w) - fmaxf(ub.x, bp.z), 0.0f);
            float un1 = (bp.w - bp.z) + ul - in1;
            float io1 = in1 / fmaxf(un1, 1e-12f);
            if (io0 > OVERLAP) word |= (1ull << (2 * jj));
            if (io1 > OVERLAP) word |= (1ull << (2 * jj + 1));
        }
        if (w == g) word &= (1ull << lane) - 1ull;          // diagonal: only j < u
        { int rem = V - (w << 6); if (rem < 64) word &= (1ull << rem) - 1ull; }
        if (ui >= V) word = 0ull;
        mat[((size_t)TRI(g, w) << 6) + lane] = word;
    }
}

// ========== K4': zero slab + word-sequential greedy fixpoint + scatter ==========
__global__ __launch_bounds__(512) void k4_fix(
    float* __restrict__ out, unsigned char* __restrict__ ws)
{
    const int tid = threadIdx.x, lane = tid & 63, seg = tid >> 6;
    const int bc = blockIdx.x;
    const int* vc = (const int*)(ws + OFF_VCNT) + (bc << 5);
    int V = 0;
#pragma unroll
    for (int t = 0; t < 32; ++t) V += vc[t];
    const unsigned char* pb = ws + HEAD + (size_t)bc * PSTRIDE;
    const float2*             sbox = (const float2*)(pb + POFF_SBOX);
    const float*              ssc  = (const float*)(pb + POFF_SSC);
    const unsigned short*     sid  = (const unsigned short*)(pb + POFF_SID);
    const unsigned long long* mat  = (const unsigned long long*)(pb + POFF_MAT);
    __shared__ unsigned long long s_kv[32];

    // zero this bc's out slab (out touched only here; barrier drains before scatter)
    float* outb = out + (size_t)bc * N_ANCHORS * 3;
    {
        float4 z4 = make_float4(0.f, 0.f, 0.f, 0.f);
        float4* ob4 = (float4*)outb;
        for (int i = tid; i < (N_ANCHORS * 3) / 4; i += 512) ob4[i] = z4;
    }
    if (tid < 32) s_kv[tid] = 0ull;
    __syncthreads();

    const int W = (V + 63) >> 6;
    if (seg == 0) {                              // wave 0: word-sequential fixpoint
        for (int g = 0; g < W; ++g) {
            unsigned long long dl_or = 0ull;
            for (int w = 0; w < g; ++w) {
                unsigned long long rw = mat[((size_t)TRI(g, w) << 6) + lane];
                dl_or |= rw & s_kv[w];
            }
            unsigned long long rself = mat[((size_t)TRI(g, g) << 6) + lane];
            int rem = V - (g << 6);
            unsigned long long valid = (rem >= 64) ? ~0ull : ((1ull << rem) - 1ull);
            unsigned long long cand = valid & ~__ballot(dl_or != 0ull);
            unsigned long long kw = 0ull;
            while (cand) {                       // in-word greedy levels
                unsigned long long suppw = __ballot((rself & cand) != 0ull);
                unsigned long long nk = cand & ~suppw;
                if (!nk) nk = cand & (~cand + 1ull);     // acyclic: unreachable
                kw |= nk;
                unsigned long long ddw = __ballot((rself & nk) != 0ull);
                cand &= ~(nk | ddw);
            }
            if (lane == 0) s_kv[g] = kw;
        }
    }
    __syncthreads();

    for (int r = tid; r < V; r += 512) {
        if ((s_kv[r >> 6] >> (r & 63)) & 1ull) {
            float2 bx = sbox[r];
            if (bx.x > -10.0f && bx.y < 10.0f) {
                int n = sid[r];
                float* o = outb + (size_t)n * 3;
                o[0] = bx.x;
                o[1] = bx.y;
                o[2] = ssc[r];
            }
        }
    }
}

// =============== fallback: monolithic kernel (ws too small) ===============
#define BLOCK 512
#define OFF_CSC   0
#define OFF_CBX   8208
#define OFF_CID   24592
#define OFF_SBOX  0
#define OFF_SSC   16896
#define OFF_SID   25088
#define POOL_SZ   29184

__global__ __launch_bounds__(BLOCK) void det_mono(
    const float* __restrict__ loc, const float* __restrict__ cls,
    const float* __restrict__ defs, float* __restrict__ out)
{
#pragma clang fp contract(off)
    const int tid  = threadIdx.x;
    const int lane = tid & 63;
    const int wid  = tid >> 6;
    const int bc   = blockIdx.x;
    const int b    = bc >> 2;
    const int c    = bc & 3;

    __shared__ __align__(16) unsigned char pool[POOL_SZ];
    __shared__ __align__(16) unsigned long long suprowT[8 * 512];
    __shared__ unsigned long long keptg[32];
    __shared__ unsigned long long s_deadw[8];
    __shared__ int s_wsum[8], s_woff[8], s_V;

    float*          csc  = (float*)(pool + OFF_CSC);
    float2*         cbx  = (float2*)(pool + OFF_CBX);
    unsigned short* cid  = (unsigned short*)(pool + OFF_CID);
    float2*         sbox = (float2*)(pool + OFF_SBOX);
    float*          ssc  = (float*)(pool + OFF_SSC);
    unsigned short* sid  = (unsigned short*)(pool + OFF_SID);

    float* const outb = out + (size_t)bc * N_ANCHORS * 3;
    {
        float4 z4 = make_float4(0.f, 0.f, 0.f, 0.f);
        float4* ob4 = (float4*)outb;
        for (int i = tid; i < (N_ANCHORS * 3) / 4; i += BLOCK) ob4[i] = z4;
    }
    if (tid < 32) keptg[tid] = 0ull;

    const int base = tid * 4;
    float c20[20], l8v[8], d8v[8];
    {
        const float4* cp4 = (const float4*)(cls + ((size_t)b * N_ANCHORS + base) * 5);
#pragma unroll
        for (int q = 0; q < 5; ++q) ((float4*)c20)[q] = cp4[q];
        const float4* lp4 = (const float4*)(loc + ((size_t)b * N_ANCHORS + base) * 2);
        ((float4*)l8v)[0] = lp4[0]; ((float4*)l8v)[1] = lp4[1];
        const float4* dp4 = (const float4*)(defs + (size_t)base * 2);
        ((float4*)d8v)[0] = dp4[0]; ((float4*)d8v)[1] = dp4[1];
    }
    float sc4[4], bs4[4], be4[4];
    int vmask = 0, cnt = 0;
#pragma unroll
    for (int k = 0; k < 4; ++k) {
        float x0 = c20[5*k+0], x1 = c20[5*k+1], x2 = c20[5*k+2],
              x3 = c20[5*k+3], x4 = c20[5*k+4];
        float m  = fmaxf(fmaxf(fmaxf(fmaxf(x0, x1), x2), x3), x4);
        float e0 = expf(x0 - m), e1 = expf(x1 - m), e2 = expf(x2 - m),
              e3 = expf(x3 - m), e4 = expf(x4 - m);
        float sum = e0 + e1 + e2 + e3 + e4;
        float ec  = (c == 0) ? e1 : (c == 1) ? e2 : (c == 2) ? e3 : e4;
        float score = ec / sum;
        float l0 = l8v[2*k], l1 = l8v[2*k+1];
        float d0 = d8v[2*k], d1 = d8v[2*k+1];
        float cc = d0 + l0 * d1;
        float w  = d1 * expf(l1);
        sc4[k] = score;
        bs4[k] = cc - 0.5f * w;
        be4[k] = cc + 0.5f * w;
        if (score > THRESH) { vmask |= (1 << k); cnt++; }
    }

    int inc = cnt;
    for (int d = 1; d < 64; d <<= 1) {
        int v = __shfl_up(inc, d);
        if (lane >= d) inc += v;
    }
    if (lane == 63) s_wsum[wid] = inc;
    __syncthreads();
    if (tid == 0) {
        int o = 0;
        for (int w = 0; w < 8; ++w) { s_woff[w] = o; o += s_wsum[w]; }
        s_V = o;
    }
    __syncthreads();
    {
        int off = s_woff[wid] + (inc - cnt);
#pragma unroll
        for (int k = 0; k < 4; ++k) {
            if (vmask & (1 << k)) {
                csc[off] = sc4[k];
                cbx[off] = make_float2(bs4[k], be4[k]);
                cid[off] = (unsigned short)(base + k);
                off++;
            }
        }
    }
    __syncthreads();
    const int V = s_V;
    const int SCend = ((V + 511) >> 9) << 9;
    if (tid < 4) csc[V + tid] = -INFINITY;
    __syncthreads();

#define RANKCMP(sv, ib, off2, mref, rref)                                   \
    rref += ((sv) > (mref) || ((sv) == (mref) && (ib) + (off2) < pcmp)) ? 1 : 0;
    int rr[4]; float2 rb[4]; float rs[4]; int ridv[4]; int nown = 0;
    if (V <= 512) {
        if (tid < 256) {
            int   p0 = tid, p1 = tid + 256;
            bool  a0 = p0 < V, a1 = p1 < V;
            float m0 = a0 ? csc[p0] : INFINITY;
            float m1 = a1 ? csc[p1] : INFINITY;
            int   r0 = 0, r1 = 0;
            const float4* cs4 = (const float4*)csc;
            const int n4 = (V + 3) >> 2;
            for (int i4 = 0; i4 < n4; ++i4) {
                float4 s4 = cs4[i4];
                int ib = i4 << 2;
                { int pcmp = p0;
                  RANKCMP(s4.x, ib, 0, m0, r0) RANKCMP(s4.y, ib, 1, m0, r0)
                  RANKCMP(s4.z, ib, 2, m0, r0) RANKCMP(s4.w, ib, 3, m0, r0) }
                { int pcmp = p1;
                  RANKCMP(s4.x, ib, 0, m1, r1) RANKCMP(s4.y, ib, 1, m1, r1)
                  RANKCMP(s4.z, ib, 2, m1, r1) RANKCMP(s4.w, ib, 3, m1, r1) }
            }
            if (a0) { rr[nown] = r0; rb[nown] = cbx[p0]; rs[nown] = m0; ridv[nown] = cid[p0]; nown++; }
            if (a1) { rr[nown] = r1; rb[nown] = cbx[p1]; rs[nown] = m1; ridv[nown] = cid[p1]; nown++; }
        }
    } else {
        for (int p = tid; p < V; p += BLOCK) {
            float s = csc[p];
            int r = 0;
            const float4* cs4 = (const float4*)csc;
            const int n4 = (V + 3) >> 2;
            for (int i4 = 0; i4 < n4; ++i4) {
                float4 s4 = cs4[i4];
                int ib = i4 << 2;
                int pcmp = p;
                RANKCMP(s4.x, ib, 0, s, r) RANKCMP(s4.y, ib, 1, s, r)
                RANKCMP(s4.z, ib, 2, s, r) RANKCMP(s4.w, ib, 3, s, r)
            }
            rr[nown] = r; rb[nown] = cbx[p]; rs[nown] = s; ridv[nown] = cid[p]; nown++;
        }
    }
#undef RANKCMP
    __syncthreads();
    for (int q = 0; q < nown; ++q) {
        sbox[rr[q]] = rb[q];
        ssc[rr[q]]  = rs[q];
        sid[rr[q]]  = (unsigned short)ridv[q];
    }
    for (int i = V + tid; i < SCend; i += BLOCK)
        sbox[i] = make_float2(1e30f, 1e30f);
    __syncthreads();

    for (int s0 = 0; s0 < V; s0 += 512) {
        const int scn = (V - s0 < 512) ? (V - s0) : 512;
        const int i   = tid;
        float2 my = sbox[s0 + i];
        float  ml = my.y - my.x;

        bool dead = false;
        const int ew_n = s0 >> 6;
        for (int ew = 0; ew < ew_n; ++ew) {
            unsigned long long kw = keptg[ew];
            if (kw) {
                const float4* sb4 = (const float4*)(sbox + (ew << 6));
#pragma unroll
                for (int jj = 0; jj < 32; ++jj) {
                    float4 bp = sb4[jj];
                    float in0 = fmaxf(fminf(my.y, bp.y) - fmaxf(my.x, bp.x), 0.0f);
                    float un0 = (bp.y - bp.x) + ml - in0;
                    float io0 = in0 / fmaxf(un0, 1e-12f);
                    float in1 = fmaxf(fminf(my.y, bp.w) - fmaxf(my.x, bp.z), 0.0f);
                    float un1 = (bp.w - bp.z) + ml - in1;
                    float io1 = in1 / fmaxf(un1, 1e-12f);
                    unsigned long long bits = kw >> (2 * jj);
                    dead |= (io0 > OVERLAP) && ((bits & 1ull) != 0ull);
                    dead |= (io1 > OVERLAP) && ((bits & 2ull) != 0ull);
                }
            }
        }
        {
            unsigned long long db = __ballot(dead && (i < scn));
            if (lane == 0) s_deadw[wid] = db;
        }

        {
            int t = 0;
#pragma unroll
            for (int k = 0; k < 8; ++k) {
#pragma unroll
                for (int w = 0; w <= k; ++w, ++t) {
                    if ((t & 7) == wid) {
                        const int u = (k << 6) + lane;
                        float2 ub = sbox[s0 + u];
                        float  ul = ub.y - ub.x;
                        const float4* sb4 = (const float4*)(sbox + s0 + (w << 6));
                        unsigned long long word = 0ull;
                        if (w == k) {
#pragma unroll
                            for (int jj = 0; jj < 32; ++jj) {
                                float4 bp = sb4[jj];
                                float in0 = fmaxf(fminf(ub.y, bp.y) - fmaxf(ub.x, bp.x), 0.0f);
                                float un0 = (bp.y - bp.x) + ul - in0;
                                float io0 = in0 / fmaxf(un0, 1e-12f);
                                float in1 = fmaxf(fminf(ub.y, bp.w) - fmaxf(ub.x, bp.z), 0.0f);
                                float un1 = (bp.w - bp.z) + ul - in1;
                                float io1 = in1 / fmaxf(un1, 1e-12f);
                                if (io0 > OVERLAP && 2 * jj     < lane) word |= (1ull << (2 * jj));
                                if (io1 > OVERLAP && 2 * jj + 1 < lane) word |= (1ull << (2 * jj + 1));
                            }
                        } else {
#pragma unroll
                            for (int jj = 0; jj < 32; ++jj) {
                                float4 bp = sb4[jj];
                                float in0 = fmaxf(fminf(ub.y, bp.y) - fmaxf(ub.x, bp.x), 0.0f);
                                float un0 = (bp.y - bp.x) + ul - in0;
                                float io0 = in0 / fmaxf(un0, 1e-12f);
                                float in1 = fmaxf(fminf(ub.y, bp.w) - fmaxf(ub.x, bp.z), 0.0f);
                                float un1 = (bp.w - bp.z) + ul - in1;
                                float io1 = in1 / fmaxf(un1, 1e-12f);
                                if (io0 > OVERLAP) word |= (1ull << (2 * jj));
                                if (io1 > OVERLAP) word |= (1ull << (2 * jj + 1));
                            }
                        }
                        suprowT[(w << 9) + u] = word;
                    }
                }
            }
        }
        __syncthreads();

        if (wid == 0) {
            unsigned long long row[36];
#pragma unroll
            for (int k = 0; k < 8; ++k)
#pragma unroll
                for (int w = 0; w <= k; ++w)
                    row[TRI(k, w)] = suprowT[(w << 9) + (k << 6) + lane];
            unsigned long long sdead[8];
#pragma unroll
            for (int w = 0; w < 8; ++w) sdead[w] = s_deadw[w];

            unsigned long long kv[8];
#pragma unroll
            for (int w = 0; w < 8; ++w) {
                kv[w] = 0ull;
                if ((w << 6) < scn) {
                    bool dl = ((sdead[w] >> lane) & 1ull) != 0ull;
#pragma unroll
                    for (int w2 = 0; w2 < w; ++w2)
                        dl |= (row[TRI(w, w2)] & kv[w2]) != 0ull;
                    const unsigned long long rself = row[TRI(w, w)];
                    int rem = scn - (w << 6);
                    unsigned long long valid = (rem >= 64) ? ~0ull : ((1ull << rem) - 1ull);
                    unsigned long long cand = valid & ~__ballot(dl);
                    unsigned long long kw = 0ull;
                    while (cand) {
                        unsigned long long suppw = __ballot((rself & cand) != 0ull);
                        unsigned long long nk = cand & ~suppw;
                        if (!nk) nk = cand & (~cand + 1ull);
                        kw |= nk;
                        unsigned long long ddw = __ballot((rself & nk) != 0ull);
                        cand &= ~(nk | ddw);
                    }
                    kv[w] = kw;
                }
            }
            if (lane == 0) {
#pragma unroll
                for (int w = 0; w < 8; ++w) keptg[(s0 >> 6) + w] |= kv[w];
            }
        }
        __syncthreads();
    }

    for (int r = tid; r < V; r += BLOCK) {
        if ((keptg[r >> 6] >> (r & 63)) & 1ull) {
            float2 bx = sbox[r];
            if (bx.x > -10.0f && bx.y < 10.0f) {
                int n = sid[r];
                float* o = outb + (size_t)n * 3;
                o[0] = bx.x;
                o[1] = bx.y;
                o[2] = ssc[r];
            }
        }
    }
}

extern "C" void kernel_launch(void* const* d_in, const int* in_sizes, int n_in,
                              void* d_out, int out_size, void* d_ws, size_t ws_size,
                              hipStream_t stream) {
    const float* loc  = (const float*)d_in[0];  // localizations (8,2048,2)
    const float* cls  = (const float*)d_in[1];  // classifications (8,2048,5)
    const float* defs = (const float*)d_in[2];  // localizations_default (2048,2)
    float* out = (float*)d_out;                 // (8,4,2048,3) fp32
    if (ws_size >= WS_NEED) {
        unsigned char* ws = (unsigned char*)d_ws;
        k2_rankdec<<<1024, 512, 0, stream>>>(loc, cls, defs, ws);
        k3_full   <<<1024, 512, 0, stream>>>(ws);
        k4_fix    <<<32, 512, 0, stream>>>(out, ws);
    } else {
        det_mono<<<NBC, BLOCK, 0, stream>>>(loc, cls, defs, out);
    }
}

// Round 15
// 108.256 us; speedup vs baseline: 3.0581x; 1.1011x over previous
//
#include <hip/hip_runtime.h>
#include <math.h>

#define N_ANCHORS 2048
#define THRESH 0.3f
#define OVERLAP 0.5f
#define NBC 32
#define TRI(k, w) ((k) * ((k) + 1) / 2 + (w))   // triangular unit index

// ---- workspace: Vs[32] at byte 0, then per-bc regions ----
#define VS_BYTES   128
#define WOFF_CSC   0        // float[2048]   score, compacted (anchor order)
#define WOFF_CBX   8192     // float2[2048]  box,   compacted
#define WOFF_CID   24576    // ushort[2048]  anchor id, compacted
#define WOFF_SBOX  28672    // float2[2048]  box, sorted order
#define WOFF_SSC   45056    // float[2048]   score, sorted order
#define WOFF_SID   53248    // ushort[2048]  anchor id, sorted order
#define WOFF_MAT   57344    // u64[528*64]   full triangular suppression matrix
#define STRIDE2    327680
#define WS_NEED    (VS_BYTES + (size_t)NBC * STRIDE2)   // ~10.5 MB

// ============================ K1: decode + compact ============================
__global__ __launch_bounds__(512) void k1_decode(
    const float* __restrict__ loc, const float* __restrict__ cls,
    const float* __restrict__ defs, unsigned char* __restrict__ ws)
{
#pragma clang fp contract(off)
    const int tid = threadIdx.x, lane = tid & 63, wid = tid >> 6;
    const int bc = blockIdx.x, b = bc >> 2, c = bc & 3;
    __shared__ int s_wsum[8], s_woff[8];

    const int base = tid * 4;
    float c20[20], l8v[8], d8v[8];
    {
        const float4* cp4 = (const float4*)(cls + ((size_t)b * N_ANCHORS + base) * 5);
#pragma unroll
        for (int q = 0; q < 5; ++q) ((float4*)c20)[q] = cp4[q];
        const float4* lp4 = (const float4*)(loc + ((size_t)b * N_ANCHORS + base) * 2);
        ((float4*)l8v)[0] = lp4[0]; ((float4*)l8v)[1] = lp4[1];
        const float4* dp4 = (const float4*)(defs + (size_t)base * 2);
        ((float4*)d8v)[0] = dp4[0]; ((float4*)d8v)[1] = dp4[1];
    }
    float sc4[4], bs4[4], be4[4];
    int vmask = 0, cnt = 0;
#pragma unroll
    for (int k = 0; k < 4; ++k) {
        float x0 = c20[5*k+0], x1 = c20[5*k+1], x2 = c20[5*k+2],
              x3 = c20[5*k+3], x4 = c20[5*k+4];
        float m  = fmaxf(fmaxf(fmaxf(fmaxf(x0, x1), x2), x3), x4);
        float e0 = expf(x0 - m), e1 = expf(x1 - m), e2 = expf(x2 - m),
              e3 = expf(x3 - m), e4 = expf(x4 - m);
        float sum = e0 + e1 + e2 + e3 + e4;
        float ec  = (c == 0) ? e1 : (c == 1) ? e2 : (c == 2) ? e3 : e4;
        float score = ec / sum;
        float l0 = l8v[2*k], l1 = l8v[2*k+1];
        float d0 = d8v[2*k], d1 = d8v[2*k+1];
        float cc = d0 + l0 * d1;
        float w  = d1 * expf(l1);
        sc4[k] = score;
        bs4[k] = cc - 0.5f * w;
        be4[k] = cc + 0.5f * w;
        if (score > THRESH) { vmask |= (1 << k); cnt++; }
    }

    // ordered compaction (compacted order == anchor order == tie-break order)
    int inc = cnt;
    for (int d = 1; d < 64; d <<= 1) {
        int v = __shfl_up(inc, d);
        if (lane >= d) inc += v;
    }
    if (lane == 63) s_wsum[wid] = inc;
    __syncthreads();
    if (tid == 0) {
        int o = 0;
        for (int w = 0; w < 8; ++w) { s_woff[w] = o; o += s_wsum[w]; }
        ((int*)ws)[bc] = o;
    }
    __syncthreads();
    unsigned char* wsb = ws + VS_BYTES + (size_t)bc * STRIDE2;
    float*          wcsc = (float*)(wsb + WOFF_CSC);
    float2*         wcbx = (float2*)(wsb + WOFF_CBX);
    unsigned short* wcid = (unsigned short*)(wsb + WOFF_CID);
    int off = s_woff[wid] + (inc - cnt);
#pragma unroll
    for (int k = 0; k < 4; ++k) {
        if (vmask & (1 << k)) {
            wcsc[off] = sc4[k];
            wcbx[off] = make_float2(bs4[k], be4[k]);
            wcid[off] = (unsigned short)(base + k);
            off++;
        }
    }
}

// ===================== K2: counting rank (64 candidates/block) =====================
// rank(q) = #{i<V : s_i > s_q  or (s_i == s_q and i < q)} — stable argsort order.
// Ranks are a permutation -> scatter writes race-free across blocks.
__global__ __launch_bounds__(256) void k2_rank(unsigned char* __restrict__ ws)
{
    const int bx = blockIdx.x;
    const int bc = bx >> 5, j = bx & 31;
    const int V = ((const int*)ws)[bc];
    if ((j << 6) >= V) return;                  // early-return beyond V
    unsigned char* wsb = ws + VS_BYTES + (size_t)bc * STRIDE2;
    const float*          csc = (const float*)(wsb + WOFF_CSC);
    const float2*         cbx = (const float2*)(wsb + WOFF_CBX);
    const unsigned short* cid = (const unsigned short*)(wsb + WOFF_CID);
    float2*         sbox = (float2*)(wsb + WOFF_SBOX);
    float*          ssc  = (float*)(wsb + WOFF_SSC);
    unsigned short* sid  = (unsigned short*)(wsb + WOFF_SID);

    const int tid = threadIdx.x, lane = tid & 63, seg = tid >> 6;
    const int q = (j << 6) + lane;
    const bool aq = q < V;
    float m = aq ? csc[q] : INFINITY;
    const int Q = (V + 3) >> 2;
    int i0 = seg * Q, i1 = i0 + Q;
    if (i1 > V) i1 = V;
    int r = 0;
#pragma unroll 4
    for (int i = i0; i < i1; ++i) {             // wave-uniform stream -> scalar loads
        float s = csc[i];
        r += (s > m || (s == m && i < q)) ? 1 : 0;
    }
    __shared__ int part[256];
    part[tid] = r;
    __syncthreads();
    if (seg == 0 && aq) {
        int R = part[lane] + part[64 + lane] + part[128 + lane] + part[192 + lane];
        sbox[R] = cbx[q];
        ssc[R]  = m;
        sid[R]  = cid[q];
    }
}

// ============ K3: FULL triangular suppression matrix (stripe g per block) ============
// Kept-independent: every IoU pair computed here at up-to-1024-block parallelism.
__global__ __launch_bounds__(512) void k3_full(unsigned char* __restrict__ ws)
{
#pragma clang fp contract(off)
    const int bx = blockIdx.x;
    const int bc = bx >> 5, g = bx & 31;
    const int V = ((const int*)ws)[bc];
    if ((g << 6) >= V) return;                  // early-return beyond V
    const int tid = threadIdx.x, lane = tid & 63, wid = tid >> 6;
    unsigned char* wsb = ws + VS_BYTES + (size_t)bc * STRIDE2;
    const float2* sbox = (const float2*)(wsb + WOFF_SBOX);
    unsigned long long* mat = (unsigned long long*)(wsb + WOFF_MAT);

    const int u = (g << 6) + lane;
    float2 ub = (u < V) ? sbox[u] : make_float2(1e30f, 1e30f);
    float  ul = ub.y - ub.x;
    for (int w = wid; w <= g; w += 8) {         // words round-robin over 8 waves
        const float4* sb4 = (const float4*)(sbox + (w << 6));
        unsigned long long word = 0ull;
        for (int jj = 0; jj < 32; ++jj) {
            float4 bp = sb4[jj];
            float in0 = fmaxf(fminf(ub.y, bp.y) - fmaxf(ub.x, bp.x), 0.0f);
            float un0 = (bp.y - bp.x) + ul - in0;
            float io0 = in0 / fmaxf(un0, 1e-12f);
            float in1 = fmaxf(fminf(ub.y, bp.w) - fmaxf(ub.x, bp.z), 0.0f);
            float un1 = (bp.w - bp.z) + ul - in1;
            float io1 = in1 / fmaxf(un1, 1e-12f);
            if (io0 > OVERLAP) word |= (1ull << (2 * jj));
            if (io1 > OVERLAP) word |= (1ull << (2 * jj + 1));
        }
        if (w == g) word &= (1ull << lane) - 1ull;          // diagonal: only j < u
        { int rem = V - (w << 6); if (rem < 64) word &= (1ull << rem) - 1ull; }
        if (u >= V) word = 0ull;
        mat[((size_t)TRI(g, w) << 6) + lane] = word;
    }
}

// ========== K4: zero slab + word-sequential greedy fixpoint (wave 0) + scatter ==========
__global__ __launch_bounds__(512) void k4_fix(
    float* __restrict__ out, unsigned char* __restrict__ ws)
{
    const int tid = threadIdx.x, lane = tid & 63, wid = tid >> 6;
    const int bc = blockIdx.x;
    const int V = ((const int*)ws)[bc];
    const unsigned char* wsb = ws + VS_BYTES + (size_t)bc * STRIDE2;
    const float2*             sbox = (const float2*)(wsb + WOFF_SBOX);
    const float*              ssc  = (const float*)(wsb + WOFF_SSC);
    const unsigned short*     sid  = (const unsigned short*)(wsb + WOFF_SID);
    const unsigned long long* mat  = (const unsigned long long*)(wsb + WOFF_MAT);
    __shared__ unsigned long long s_kv[32];

    // zero this bc's out slab (out touched ONLY here; barrier drains before scatter)
    float* outb = out + (size_t)bc * N_ANCHORS * 3;
    {
        float4 z4 = make_float4(0.f, 0.f, 0.f, 0.f);
        float4* ob4 = (float4*)outb;
        for (int i = tid; i < (N_ANCHORS * 3) / 4; i += 512) ob4[i] = z4;
    }
    if (tid < 32) s_kv[tid] = 0ull;
    __syncthreads();

    const int W = (V + 63) >> 6;
    if (wid == 0) {                              // wave 0: word-sequential fixpoint
        for (int g = 0; g < W; ++g) {
            // box u = 64g+lane dead iff some kept j in an earlier word suppresses it
            unsigned long long dl_or = 0ull;
            for (int w = 0; w < g; ++w) {
                unsigned long long rw = mat[((size_t)TRI(g, w) << 6) + lane];
                dl_or |= rw & s_kv[w];
            }
            unsigned long long rself = mat[((size_t)TRI(g, g) << 6) + lane];
            int rem = V - (g << 6);
            unsigned long long valid = (rem >= 64) ? ~0ull : ((1ull << rem) - 1ull);
            unsigned long long cand = valid & ~__ballot(dl_or != 0ull);
            unsigned long long kw = 0ull;
            while (cand) {                       // in-word greedy levels
                unsigned long long suppw = __ballot((rself & cand) != 0ull);
                unsigned long long nk = cand & ~suppw;
                if (!nk) nk = cand & (~cand + 1ull);     // acyclic: unreachable
                kw |= nk;
                unsigned long long ddw = __ballot((rself & nk) != 0ull);
                cand &= ~(nk | ddw);
            }
            if (lane == 0) s_kv[g] = kw;
        }
    }
    __syncthreads();

    for (int r = tid; r < V; r += 512) {
        if ((s_kv[r >> 6] >> (r & 63)) & 1ull) {
            float2 bx = sbox[r];
            if (bx.x > -10.0f && bx.y < 10.0f) {
                int n = sid[r];
                float* o = outb + (size_t)n * 3;
                o[0] = bx.x;
                o[1] = bx.y;
                o[2] = ssc[r];
            }
        }
    }
}

// =============== fallback: monolithic kernel (ws too small) ===============
#define BLOCK 512
#define OFF_CSC   0
#define OFF_CBX   8208
#define OFF_CID   24592
#define OFF_SBOX  0
#define OFF_SSC   16896
#define OFF_SID   25088
#define POOL_SZ   29184

__global__ __launch_bounds__(BLOCK) void det_mono(
    const float* __restrict__ loc, const float* __restrict__ cls,
    const float* __restrict__ defs, float* __restrict__ out)
{
#pragma clang fp contract(off)
    const int tid  = threadIdx.x;
    const int lane = tid & 63;
    const int wid  = tid >> 6;
    const int bc   = blockIdx.x;
    const int b    = bc >> 2;
    const int c    = bc & 3;

    __shared__ __align__(16) unsigned char pool[POOL_SZ];
    __shared__ __align__(16) unsigned long long suprowT[8 * 512];
    __shared__ unsigned long long keptg[32];
    __shared__ unsigned long long s_deadw[8];
    __shared__ int s_wsum[8], s_woff[8], s_V;

    float*          csc  = (float*)(pool + OFF_CSC);
    float2*         cbx  = (float2*)(pool + OFF_CBX);
    unsigned short* cid  = (unsigned short*)(pool + OFF_CID);
    float2*         sbox = (float2*)(pool + OFF_SBOX);
    float*          ssc  = (float*)(pool + OFF_SSC);
    unsigned short* sid  = (unsigned short*)(pool + OFF_SID);

    float* const outb = out + (size_t)bc * N_ANCHORS * 3;
    {
        float4 z4 = make_float4(0.f, 0.f, 0.f, 0.f);
        float4* ob4 = (float4*)outb;
        for (int i = tid; i < (N_ANCHORS * 3) / 4; i += BLOCK) ob4[i] = z4;
    }
    if (tid < 32) keptg[tid] = 0ull;

    const int base = tid * 4;
    float c20[20], l8v[8], d8v[8];
    {
        const float4* cp4 = (const float4*)(cls + ((size_t)b * N_ANCHORS + base) * 5);
#pragma unroll
        for (int q = 0; q < 5; ++q) ((float4*)c20)[q] = cp4[q];
        const float4* lp4 = (const float4*)(loc + ((size_t)b * N_ANCHORS + base) * 2);
        ((float4*)l8v)[0] = lp4[0]; ((float4*)l8v)[1] = lp4[1];
        const float4* dp4 = (const float4*)(defs + (size_t)base * 2);
        ((float4*)d8v)[0] = dp4[0]; ((float4*)d8v)[1] = dp4[1];
    }
    float sc4[4], bs4[4], be4[4];
    int vmask = 0, cnt = 0;
#pragma unroll
    for (int k = 0; k < 4; ++k) {
        float x0 = c20[5*k+0], x1 = c20[5*k+1], x2 = c20[5*k+2],
              x3 = c20[5*k+3], x4 = c20[5*k+4];
        float m  = fmaxf(fmaxf(fmaxf(fmaxf(x0, x1), x2), x3), x4);
        float e0 = expf(x0 - m), e1 = expf(x1 - m), e2 = expf(x2 - m),
              e3 = expf(x3 - m), e4 = expf(x4 - m);
        float sum = e0 + e1 + e2 + e3 + e4;
        float ec  = (c == 0) ? e1 : (c == 1) ? e2 : (c == 2) ? e3 : e4;
        float score = ec / sum;
        float l0 = l8v[2*k], l1 = l8v[2*k+1];
        float d0 = d8v[2*k], d1 = d8v[2*k+1];
        float cc = d0 + l0 * d1;
        float w  = d1 * expf(l1);
        sc4[k] = score;
        bs4[k] = cc - 0.5f * w;
        be4[k] = cc + 0.5f * w;
        if (score > THRESH) { vmask |= (1 << k); cnt++; }
    }

    int inc = cnt;
    for (int d = 1; d < 64; d <<= 1) {
        int v = __shfl_up(inc, d);
        if (lane >= d) inc += v;
    }
    if (lane == 63) s_wsum[wid] = inc;
    __syncthreads();
    if (tid == 0) {
        int o = 0;
        for (int w = 0; w < 8; ++w) { s_woff[w] = o; o += s_wsum[w]; }
        s_V = o;
    }
    __syncthreads();
    {
        int off = s_woff[wid] + (inc - cnt);
#pragma unroll
        for (int k = 0; k < 4; ++k) {
            if (vmask & (1 << k)) {
                csc[off] = sc4[k];
                cbx[off] = make_float2(bs4[k], be4[k]);
                cid[off] = (unsigned short)(base + k);
                off++;
            }
        }
    }
    __syncthreads();
    const int V = s_V;
    const int SCend = ((V + 511) >> 9) << 9;
    if (tid < 4) csc[V + tid] = -INFINITY;
    __syncthreads();

#define RANKCMP(sv, ib, off2, mref, rref)                                   \
    rref += ((sv) > (mref) || ((sv) == (mref) && (ib) + (off2) < pcmp)) ? 1 : 0;
    int rr[4]; float2 rb[4]; float rs[4]; int ridv[4]; int nown = 0;
    if (V <= 512) {
        if (tid < 256) {
            int   p0 = tid, p1 = tid + 256;
            bool  a0 = p0 < V, a1 = p1 < V;
            float m0 = a0 ? csc[p0] : INFINITY;
            float m1 = a1 ? csc[p1] : INFINITY;
            int   r0 = 0, r1 = 0;
            const float4* cs4 = (const float4*)csc;
            const int n4 = (V + 3) >> 2;
            for (int i4 = 0; i4 < n4; ++i4) {
                float4 s4 = cs4[i4];
                int ib = i4 << 2;
                { int pcmp = p0;
                  RANKCMP(s4.x, ib, 0, m0, r0) RANKCMP(s4.y, ib, 1, m0, r0)
                  RANKCMP(s4.z, ib, 2, m0, r0) RANKCMP(s4.w, ib, 3, m0, r0) }
                { int pcmp = p1;
                  RANKCMP(s4.x, ib, 0, m1, r1) RANKCMP(s4.y, ib, 1, m1, r1)
                  RANKCMP(s4.z, ib, 2, m1, r1) RANKCMP(s4.w, ib, 3, m1, r1) }
            }
            if (a0) { rr[nown] = r0; rb[nown] = cbx[p0]; rs[nown] = m0; ridv[nown] = cid[p0]; nown++; }
            if (a1) { rr[nown] = r1; rb[nown] = cbx[p1]; rs[nown] = m1; ridv[nown] = cid[p1]; nown++; }
        }
    } else {
        for (int p = tid; p < V; p += BLOCK) {
            float s = csc[p];
            int r = 0;
            const float4* cs4 = (const float4*)csc;
            const int n4 = (V + 3) >> 2;
            for (int i4 = 0; i4 < n4; ++i4) {
                float4 s4 = cs4[i4];
                int ib = i4 << 2;
                int pcmp = p;
                RANKCMP(s4.x, ib, 0, s, r) RANKCMP(s4.y, ib, 1, s, r)
                RANKCMP(s4.z, ib, 2, s, r) RANKCMP(s4.w, ib, 3, s, r)
            }
            rr[nown] = r; rb[nown] = cbx[p]; rs[nown] = s; ridv[nown] = cid[p]; nown++;
        }
    }
#undef RANKCMP
    __syncthreads();
    for (int q = 0; q < nown; ++q) {
        sbox[rr[q]] = rb[q];
        ssc[rr[q]]  = rs[q];
        sid[rr[q]]  = (unsigned short)ridv[q];
    }
    for (int i = V + tid; i < SCend; i += BLOCK)
        sbox[i] = make_float2(1e30f, 1e30f);
    __syncthreads();

    for (int s0 = 0; s0 < V; s0 += 512) {
        const int scn = (V - s0 < 512) ? (V - s0) : 512;
        const int i   = tid;
        float2 my = sbox[s0 + i];
        float  ml = my.y - my.x;

        bool dead = false;
        const int ew_n = s0 >> 6;
        for (int ew = 0; ew < ew_n; ++ew) {
            unsigned long long kw = keptg[ew];
            if (kw) {
                const float4* sb4 = (const float4*)(sbox + (ew << 6));
#pragma unroll
                for (int jj = 0; jj < 32; ++jj) {
                    float4 bp = sb4[jj];
                    float in0 = fmaxf(fminf(my.y, bp.y) - fmaxf(my.x, bp.x), 0.0f);
                    float un0 = (bp.y - bp.x) + ml - in0;
                    float io0 = in0 / fmaxf(un0, 1e-12f);
                    float in1 = fmaxf(fminf(my.y, bp.w) - fmaxf(my.x, bp.z), 0.0f);
                    float un1 = (bp.w - bp.z) + ml - in1;
                    float io1 = in1 / fmaxf(un1, 1e-12f);
                    unsigned long long bits = kw >> (2 * jj);
                    dead |= (io0 > OVERLAP) && ((bits & 1ull) != 0ull);
                    dead |= (io1 > OVERLAP) && ((bits & 2ull) != 0ull);
                }
            }
        }
        {
            unsigned long long db = __ballot(dead && (i < scn));
            if (lane == 0) s_deadw[wid] = db;
        }

        {
            int t = 0;
#pragma unroll
            for (int k = 0; k < 8; ++k) {
#pragma unroll
                for (int w = 0; w <= k; ++w, ++t) {
                    if ((t & 7) == wid) {
                        const int u = (k << 6) + lane;
                        float2 ub = sbox[s0 + u];
                        float  ul = ub.y - ub.x;
                        const float4* sb4 = (const float4*)(sbox + s0 + (w << 6));
                        unsigned long long word = 0ull;
                        if (w == k) {
#pragma unroll
                            for (int jj = 0; jj < 32; ++jj) {
                                float4 bp = sb4[jj];
                                float in0 = fmaxf(fminf(ub.y, bp.y) - fmaxf(ub.x, bp.x), 0.0f);
                                float un0 = (bp.y - bp.x) + ul - in0;
                                float io0 = in0 / fmaxf(un0, 1e-12f);
                                float in1 = fmaxf(fminf(ub.y, bp.w) - fmaxf(ub.x, bp.z), 0.0f);
                                float un1 = (bp.w - bp.z) + ul - in1;
                                float io1 = in1 / fmaxf(un1, 1e-12f);
                                if (io0 > OVERLAP && 2 * jj     < lane) word |= (1ull << (2 * jj));
                                if (io1 > OVERLAP && 2 * jj + 1 < lane) word |= (1ull << (2 * jj + 1));
                            }
                        } else {
#pragma unroll
                            for (int jj = 0; jj < 32; ++jj) {
                                float4 bp = sb4[jj];
                                float in0 = fmaxf(fminf(ub.y, bp.y) - fmaxf(ub.x, bp.x), 0.0f);
                                float un0 = (bp.y - bp.x) + ul - in0;
                                float io0 = in0 / fmaxf(un0, 1e-12f);
                                float in1 = fmaxf(fminf(ub.y, bp.w) - fmaxf(ub.x, bp.z), 0.0f);
                                float un1 = (bp.w - bp.z) + ul - in1;
                                float io1 = in1 / fmaxf(un1, 1e-12f);
                                if (io0 > OVERLAP) word |= (1ull << (2 * jj));
                                if (io1 > OVERLAP) word |= (1ull << (2 * jj + 1));
                            }
                        }
                        suprowT[(w << 9) + u] = word;
                    }
                }
            }
        }
        __syncthreads();

        if (wid == 0) {
            unsigned long long row[36];
#pragma unroll
            for (int k = 0; k < 8; ++k)
#pragma unroll
                for (int w = 0; w <= k; ++w)
                    row[TRI(k, w)] = suprowT[(w << 9) + (k << 6) + lane];
            unsigned long long sdead[8];
#pragma unroll
            for (int w = 0; w < 8; ++w) sdead[w] = s_deadw[w];

            unsigned long long kv[8];
#pragma unroll
            for (int w = 0; w < 8; ++w) {
                kv[w] = 0ull;
                if ((w << 6) < scn) {
                    bool dl = ((sdead[w] >> lane) & 1ull) != 0ull;
#pragma unroll
                    for (int w2 = 0; w2 < w; ++w2)
                        dl |= (row[TRI(w, w2)] & kv[w2]) != 0ull;
                    const unsigned long long rself = row[TRI(w, w)];
                    int rem = scn - (w << 6);
                    unsigned long long valid = (rem >= 64) ? ~0ull : ((1ull << rem) - 1ull);
                    unsigned long long cand = valid & ~__ballot(dl);
                    unsigned long long kw = 0ull;
                    while (cand) {
                        unsigned long long suppw = __ballot((rself & cand) != 0ull);
                        unsigned long long nk = cand & ~suppw;
                        if (!nk) nk = cand & (~cand + 1ull);
                        kw |= nk;
                        unsigned long long ddw = __ballot((rself & nk) != 0ull);
                        cand &= ~(nk | ddw);
                    }
                    kv[w] = kw;
                }
            }
            if (lane == 0) {
#pragma unroll
                for (int w = 0; w < 8; ++w) keptg[(s0 >> 6) + w] |= kv[w];
            }
        }
        __syncthreads();
    }

    for (int r = tid; r < V; r += BLOCK) {
        if ((keptg[r >> 6] >> (r & 63)) & 1ull) {
            float2 bx = sbox[r];
            if (bx.x > -10.0f && bx.y < 10.0f) {
                int n = sid[r];
                float* o = outb + (size_t)n * 3;
                o[0] = bx.x;
                o[1] = bx.y;
                o[2] = ssc[r];
            }
        }
    }
}

extern "C" void kernel_launch(void* const* d_in, const int* in_sizes, int n_in,
                              void* d_out, int out_size, void* d_ws, size_t ws_size,
                              hipStream_t stream) {
    const float* loc  = (const float*)d_in[0];  // localizations (8,2048,2)
    const float* cls  = (const float*)d_in[1];  // classifications (8,2048,5)
    const float* defs = (const float*)d_in[2];  // localizations_default (2048,2)
    float* out = (float*)d_out;                 // (8,4,2048,3) fp32
    if (ws_size >= WS_NEED) {
        unsigned char* ws = (unsigned char*)d_ws;
        k1_decode<<<NBC, 512, 0, stream>>>(loc, cls, defs, ws);
        k2_rank  <<<NBC * 32, 256, 0, stream>>>(ws);
        k3_full  <<<NBC * 32, 512, 0, stream>>>(ws);
        k4_fix   <<<NBC, 512, 0, stream>>>(out, ws);
    } else {
        det_mono<<<NBC, BLOCK, 0, stream>>>(loc, cls, defs, out);
    }
}